// Round 6
// baseline (835.788 us; speedup 1.0000x reference)
//
#include <hip/hip_runtime.h>
#include <hip/hip_bf16.h>

// Problem constants (from reference)
#define S_LEN   2048
#define BATCH   4
#define IN_DIM  64
#define H_DIM   1024
#define DFF_DIM 1024
#define OUT_DIM 64
#define NLAYER  3
#define NHEADS  4
#define DHEAD   256     // H / NHEAD
#define WIN     4       // banded window: j in [i-4, i]
#define ROWS    (S_LEN*BATCH)  // 8192 flattened (s,b) rows, row = s*B + b
#define QKV_LD  (3*H_DIM)      // 3072

// Established facts (rounds 0-5):
//  - inputs fp32; OUTPUT fp32 (threshold = 0.02 * max|ref| exactly => no bf16
//    anywhere in the harness check; rounds 1-2 NaN'd reading inputs as bf16)
//  - rounds 3 and 4 (MFMA vs VALU pipelines) gave bit-identical absmax =>
//    both compute engines + attn kernels + LN + 104 MiB ws footprint are
//    mutually validated; only the d_out store dtype was wrong (bf16 vs fp32).
//  - seq-major row layout (row = s*B+b), window keys rows (s-4..s)*B+b.

typedef __bf16 bf16x8 __attribute__((ext_vector_type(8)));
typedef float  f32x4  __attribute__((ext_vector_type(4)));

__device__ __forceinline__ float bfbits2f(unsigned int u) {
  union { unsigned int i; float f; } c; c.i = u << 16; return c.f;
}
__device__ __forceinline__ unsigned short f2bfbits(float f) {
  __hip_bfloat16 h = __float2bfloat16(f);
  return __builtin_bit_cast(unsigned short, h);
}

// fp32 -> bf16 elementwise conversion (weights/src ingest)
__global__ __launch_bounds__(256)
void cvt_k(const float* __restrict__ in, __hip_bfloat16* __restrict__ out, int n)
{
  int i = blockIdx.x * 256 + threadIdx.x;
  if (i < n) out[i] = __float2bfloat16(in[i]);
}

// ---------------------------------------------------------------------------
// GEMM: C[M,N] = A[M,K] @ B[N,K]^T + bias[N]  (optional ReLU). A,B bf16
// (B dense [N,K]), bias fp32, C bf16 (OUTF32=0) or fp32 (OUTF32=1), fp32
// accumulate. 128x128 tile, BK=32, 256 thr, 4 waves x (4x4) MFMA 16x16x32.
// Conservative staging (uint4 global->VGPR->LDS) — validated rounds 3==4.
// M%128==0, K%32==0 required; N edge via clamped B loads + guarded stores.
// ---------------------------------------------------------------------------
template<int RELU, int OUTF32>
__global__ __launch_bounds__(256, 2)
void gemm_bt(const __hip_bfloat16* __restrict__ A, int lda,
             const __hip_bfloat16* __restrict__ B,
             const float* __restrict__ bias,
             void* __restrict__ Cp, int ldc,
             int M, int N, int K)
{
  __shared__ __align__(16) __hip_bfloat16 As[128 * 32];
  __shared__ __align__(16) __hip_bfloat16 Bs[128 * 32];

  const int tid  = threadIdx.x;
  const int lane = tid & 63;
  const int wave = tid >> 6;
  const int quad = lane >> 4;
  const int l16  = lane & 15;
  const int m0 = blockIdx.y * 128;
  const int n0 = blockIdx.x * 128;
  const int wr = (wave >> 1) * 64;   // wave's 64x64 sub-tile
  const int wc = (wave & 1) * 64;

  // tile = 128 rows x 32 cols = 512 chunks of 16B (8 bf16); chunk i covers
  // row i>>2, cols (i&3)*8..+8; LDS elem offset = i*8 (row-major identity).
  const int i0  = tid;        // chunks [0,256)
  const int i1  = tid + 256;  // chunks [256,512)
  const int ar0 = i0 >> 2, ac0 = (i0 & 3) * 8;
  const int ar1 = i1 >> 2, ac1 = (i1 & 3) * 8;
  const int br0 = min(n0 + ar0, N - 1);   // clamp for N edge (loads valid
  const int br1 = min(n0 + ar1, N - 1);   // data; stores are guarded)

  f32x4 acc[4][4] = {};

  for (int k0 = 0; k0 < K; k0 += 32) {
    uint4 va0 = *(const uint4*)(A + (size_t)(m0 + ar0) * lda + k0 + ac0);
    uint4 va1 = *(const uint4*)(A + (size_t)(m0 + ar1) * lda + k0 + ac1);
    uint4 vb0 = *(const uint4*)(B + (size_t)br0 * K + k0 + ac0);
    uint4 vb1 = *(const uint4*)(B + (size_t)br1 * K + k0 + ac1);
    __syncthreads();   // previous iteration's fragment reads done
    *(uint4*)&As[i0 * 8] = va0;
    *(uint4*)&As[i1 * 8] = va1;
    *(uint4*)&Bs[i0 * 8] = vb0;
    *(uint4*)&Bs[i1 * 8] = vb1;
    __syncthreads();

    bf16x8 af[4], bfr[4];
#pragma unroll
    for (int i = 0; i < 4; i++)   // A frag: lane holds A[m=l16][k=quad*8..+7]
      af[i] = *(const bf16x8*)&As[(wr + i * 16 + l16) * 32 + quad * 8];
#pragma unroll
    for (int j = 0; j < 4; j++)   // B frag: lane holds B[n=l16][k=quad*8..+7]
      bfr[j] = *(const bf16x8*)&Bs[(wc + j * 16 + l16) * 32 + quad * 8];
#pragma unroll
    for (int i = 0; i < 4; i++)
#pragma unroll
      for (int j = 0; j < 4; j++)
        acc[i][j] = __builtin_amdgcn_mfma_f32_16x16x32_bf16(af[i], bfr[j], acc[i][j], 0, 0, 0);
  }

  // epilogue: C/D layout col = lane&15, row = quad*4 + reg
#pragma unroll
  for (int j = 0; j < 4; j++) {
    int col = n0 + wc + j * 16 + l16;
    if (col < N) {
      float bv = bias[col];
#pragma unroll
      for (int i = 0; i < 4; i++) {
        int row = m0 + wr + i * 16 + quad * 4;
#pragma unroll
        for (int r = 0; r < 4; r++) {
          float v = acc[i][j][r] + bv;
          if (RELU) v = fmaxf(v, 0.f);
          if (OUTF32) ((float*)Cp)[(size_t)(row + r) * ldc + col] = v;
          else ((__hip_bfloat16*)Cp)[(size_t)(row + r) * ldc + col] = __float2bfloat16(v);
        }
      }
    }
  }
}

// ---------------------------------------------------------------------------
// Banded attention: one wave per (s, b, h); seq-major rows (row = s*B+b).
// Window = 5 keys (j in [s-4, s]). dh=256 => 4 elems/lane. qkv rows [3H]:
// q@0, k@H, v@2H; head h at h*256. ctx overwrites the q slot (only this
// wave ever touches q[s,b,h], all its q reads precede the write).
// ---------------------------------------------------------------------------
__global__ __launch_bounds__(256)
void attn_k(__hip_bfloat16* __restrict__ qkv)
{
  const int gw   = (blockIdx.x << 2) + (threadIdx.x >> 6);
  const int lane = threadIdx.x & 63;
  const int h = gw & (NHEADS - 1);
  const int b = (gw >> 2) & (BATCH - 1);
  const int s = gw >> 4;
  const size_t hoff = (size_t)h * DHEAD + (lane << 2);

  float q0, q1, q2, q3;
  {
    uint2 t = *(const uint2*)(qkv + (size_t)(s * BATCH + b) * QKV_LD + hoff);
    q0 = bfbits2f(t.x & 0xffff); q1 = bfbits2f(t.x >> 16);
    q2 = bfbits2f(t.y & 0xffff); q3 = bfbits2f(t.y >> 16);
  }

  float sc[WIN + 1];
#pragma unroll
  for (int jj = 0; jj <= WIN; jj++) {
    int j = s - WIN + jj;           // wave-uniform
    float v = -1e30f;
    if (j >= 0) {
      uint2 t = *(const uint2*)(qkv + (size_t)(j * BATCH + b) * QKV_LD + H_DIM + hoff);
      float p = q0 * bfbits2f(t.x & 0xffff) + q1 * bfbits2f(t.x >> 16)
              + q2 * bfbits2f(t.y & 0xffff) + q3 * bfbits2f(t.y >> 16);
#pragma unroll
      for (int o = 32; o; o >>= 1) p += __shfl_xor(p, o);
      v = p * 0.0625f;              // 1/sqrt(256)
    }
    sc[jj] = v;
  }

  float mx = sc[0];
#pragma unroll
  for (int jj = 1; jj <= WIN; jj++) mx = fmaxf(mx, sc[jj]);
  float p[WIN + 1], den = 0.f;
#pragma unroll
  for (int jj = 0; jj <= WIN; jj++) { p[jj] = __expf(sc[jj] - mx); den += p[jj]; }

  float a0 = 0.f, a1 = 0.f, a2 = 0.f, a3 = 0.f;
#pragma unroll
  for (int jj = 0; jj <= WIN; jj++) {
    int j = s - WIN + jj;
    if (j >= 0) {
      uint2 t = *(const uint2*)(qkv + (size_t)(j * BATCH + b) * QKV_LD + 2 * H_DIM + hoff);
      a0 += p[jj] * bfbits2f(t.x & 0xffff); a1 += p[jj] * bfbits2f(t.x >> 16);
      a2 += p[jj] * bfbits2f(t.y & 0xffff); a3 += p[jj] * bfbits2f(t.y >> 16);
    }
  }
  float rl = 1.f / den;
  uint2 o;
  o.x = (unsigned)f2bfbits(a0 * rl) | ((unsigned)f2bfbits(a1 * rl) << 16);
  o.y = (unsigned)f2bfbits(a2 * rl) | ((unsigned)f2bfbits(a3 * rl) << 16);
  *(uint2*)(qkv + (size_t)(s * BATCH + b) * QKV_LD + hoff) = o;  // ctx -> q slot
}

// ---------------------------------------------------------------------------
// Fused residual-add + LayerNorm, in place on bf16 x. One block per row.
// x_new = (x + y - mean)/sqrt(var+eps) * g + be; fp32 params read direct.
// ---------------------------------------------------------------------------
__global__ __launch_bounds__(256)
void add_ln_k(__hip_bfloat16* __restrict__ x, const __hip_bfloat16* __restrict__ y, int ys,
              const float* __restrict__ g, const float* __restrict__ be)
{
  const int row = blockIdx.x, tid = threadIdx.x;
  const size_t base = (size_t)row * H_DIM + tid * 4;
  uint2 xv = *(const uint2*)(x + base);
  uint2 yv = *(const uint2*)(y + (size_t)row * ys + tid * 4);
  float t0 = bfbits2f(xv.x & 0xffff) + bfbits2f(yv.x & 0xffff);
  float t1 = bfbits2f(xv.x >> 16)    + bfbits2f(yv.x >> 16);
  float t2 = bfbits2f(xv.y & 0xffff) + bfbits2f(yv.y & 0xffff);
  float t3 = bfbits2f(xv.y >> 16)    + bfbits2f(yv.y >> 16);
  float s  = t0 + t1 + t2 + t3;
  float ss = t0 * t0 + t1 * t1 + t2 * t2 + t3 * t3;
#pragma unroll
  for (int o = 32; o; o >>= 1) { s += __shfl_down(s, o); ss += __shfl_down(ss, o); }
  __shared__ float rs[4], rss[4];
  if ((tid & 63) == 0) { rs[tid >> 6] = s; rss[tid >> 6] = ss; }
  __syncthreads();
  float S  = rs[0] + rs[1] + rs[2] + rs[3];
  float SS = rss[0] + rss[1] + rss[2] + rss[3];
  const float inv = 1.f / (float)H_DIM;
  float mean = S * inv;
  float var  = SS * inv - mean * mean;       // biased var (jnp.var default)
  float rstd = rsqrtf(var + 1e-5f);
  float4 gv = *(const float4*)(g + tid * 4);
  float4 bv = *(const float4*)(be + tid * 4);
  float o0 = (t0 - mean) * rstd * gv.x + bv.x;
  float o1 = (t1 - mean) * rstd * gv.y + bv.y;
  float o2 = (t2 - mean) * rstd * gv.z + bv.z;
  float o3 = (t3 - mean) * rstd * gv.w + bv.w;
  uint2 ob;
  ob.x = (unsigned)f2bfbits(o0) | ((unsigned)f2bfbits(o1) << 16);
  ob.y = (unsigned)f2bfbits(o2) | ((unsigned)f2bfbits(o3) << 16);
  *(uint2*)(x + base) = ob;
}

// ---------------------------------------------------------------------------
extern "C" void kernel_launch(void* const* d_in, const int* in_sizes, int n_in,
                              void* d_out, int out_size, void* d_ws, size_t ws_size,
                              hipStream_t stream) {
  const float* src   = (const float*)d_in[0];
  const float* Wenc  = (const float*)d_in[1];
  const float* benc  = (const float*)d_in[2];
  const float* Wqkv  = (const float*)d_in[3];
  const float* bqkv  = (const float*)d_in[4];
  const float* Wo    = (const float*)d_in[5];
  const float* bo    = (const float*)d_in[6];
  const float* W1    = (const float*)d_in[7];
  const float* b1    = (const float*)d_in[8];
  const float* W2    = (const float*)d_in[9];
  const float* b2    = (const float*)d_in[10];
  const float* ln1s  = (const float*)d_in[11];
  const float* ln1b  = (const float*)d_in[12];
  const float* ln2s  = (const float*)d_in[13];
  const float* ln2b  = (const float*)d_in[14];
  const float* Wout  = (const float*)d_in[15];
  const float* bout  = (const float*)d_in[16];

  // ---- workspace (104 MiB total — footprint validated in round 3) ----
  char* ws = (char*)d_ws;
  __hip_bfloat16* WB   = (__hip_bfloat16*)ws;      // bf16 arena (~37.3 MiB)
  __hip_bfloat16* srcb = WB;                       //   524288
  __hip_bfloat16* wenc = WB + 524288;              //    65536
  __hip_bfloat16* wqkv = WB + 589824;              //  9437184
  __hip_bfloat16* wo   = WB + 10027008;            //  3145728
  __hip_bfloat16* w1   = WB + 13172736;            //  3145728
  __hip_bfloat16* w2   = WB + 16318464;            //  3145728
  __hip_bfloat16* wout = WB + 19464192;            //    65536
  __hip_bfloat16* xb  = (__hip_bfloat16*)(ws + (size_t)40 * 1048576);  // 16 MiB
  __hip_bfloat16* qkv = (__hip_bfloat16*)(ws + (size_t)56 * 1048576);  // 48 MiB
  __hip_bfloat16* ctxp = qkv;             // q slot — attn output
  __hip_bfloat16* ybuf = qkv + H_DIM;     // k slot — attn_out / ff temp
  __hip_bfloat16* hbuf = qkv + 2 * H_DIM; // v slot — relu hidden temp

  const dim3 blk(256);
  #define CVT(inp, outp, n) cvt_k<<<dim3(((n) + 255) / 256), blk, 0, stream>>>(inp, outp, n)

  // ---- ingest: fp32 weights/src -> bf16 arenas (biases/LN stay fp32) ----
  CVT(src,  srcb, 524288);
  CVT(Wenc, wenc, 65536);
  CVT(Wqkv, wqkv, 9437184);
  CVT(Wo,   wo,   3145728);
  CVT(W1,   w1,   3145728);
  CVT(W2,   w2,   3145728);
  CVT(Wout, wout, 65536);

  // ---- encoder: x = src @ Wenc^T + benc   [8192,1024] ----
  gemm_bt<0, 0><<<dim3(H_DIM / 128, ROWS / 128), blk, 0, stream>>>(
      srcb, IN_DIM, wenc, benc, xb, H_DIM, ROWS, H_DIM, IN_DIM);

  for (int l = 0; l < NLAYER; l++) {
    // qkv = x @ Wqkv^T + bqkv   [8192,3072]
    gemm_bt<0, 0><<<dim3(QKV_LD / 128, ROWS / 128), blk, 0, stream>>>(
        xb, H_DIM, wqkv + (size_t)l * QKV_LD * H_DIM, bqkv + l * QKV_LD,
        qkv, QKV_LD, ROWS, QKV_LD, H_DIM);
    // banded attention; ctx -> q slot
    attn_k<<<dim3(ROWS * NHEADS / 4), blk, 0, stream>>>(qkv);
    // attn_out = ctx @ Wo^T + bo -> ybuf (k slot)
    gemm_bt<0, 0><<<dim3(H_DIM / 128, ROWS / 128), blk, 0, stream>>>(
        ctxp, QKV_LD, wo + (size_t)l * H_DIM * H_DIM, bo + l * H_DIM,
        ybuf, QKV_LD, ROWS, H_DIM, H_DIM);
    // x = LN(x + attn_out)
    add_ln_k<<<dim3(ROWS), blk, 0, stream>>>(xb, ybuf, QKV_LD, ln1s + l * H_DIM, ln1b + l * H_DIM);
    // h = relu(x @ W1^T + b1) -> hbuf (v slot)
    gemm_bt<1, 0><<<dim3(DFF_DIM / 128, ROWS / 128), blk, 0, stream>>>(
        xb, H_DIM, w1 + (size_t)l * DFF_DIM * H_DIM, b1 + l * DFF_DIM,
        hbuf, QKV_LD, ROWS, DFF_DIM, H_DIM);
    // ff = h @ W2^T + b2 -> ybuf (k slot)
    gemm_bt<0, 0><<<dim3(H_DIM / 128, ROWS / 128), blk, 0, stream>>>(
        hbuf, QKV_LD, w2 + (size_t)l * H_DIM * DFF_DIM, b2 + l * H_DIM,
        ybuf, QKV_LD, ROWS, H_DIM, DFF_DIM);
    // x = LN(x + ff)
    add_ln_k<<<dim3(ROWS), blk, 0, stream>>>(xb, ybuf, QKV_LD, ln2s + l * H_DIM, ln2b + l * H_DIM);
  }

  // ---- decoder: out = x @ Wout^T + bout   [8192,64] FP32 OUTPUT ----
  gemm_bt<0, 1><<<dim3(1, ROWS / 128), blk, 0, stream>>>(
      xb, H_DIM, wout, bout, d_out, OUT_DIM, ROWS, OUT_DIM, H_DIM);
}

// Round 7
// 797.106 us; speedup vs baseline: 1.0485x; 1.0485x over previous
//
#include <hip/hip_runtime.h>
#include <hip/hip_bf16.h>

// Problem constants (from reference)
#define S_LEN   2048
#define BATCH   4
#define IN_DIM  64
#define H_DIM   1024
#define DFF_DIM 1024
#define OUT_DIM 64
#define NLAYER  3
#define NHEADS  4
#define DHEAD   256     // H / NHEAD
#define WIN     4       // banded window: j in [i-4, i]
#define ROWS    (S_LEN*BATCH)  // 8192 flattened (s,b) rows, row = s*B + b
#define QKV_LD  (3*H_DIM)      // 3072

// Established facts (rounds 0-6):
//  - inputs fp32, OUTPUT fp32; seq-major rows (row = s*B+b), window stride B.
//  - round 6 PASSED (835.8 us, absmax 0.0176) with conservative staging.
//  - r6 counters: gemm 81.5us/QKV (632 TF, MfmaUtil 26%), VALUBusy 14%,
//    HBM 22%, SQ_LDS_BANK_CONFLICT 6.29M => LDS-read + staging bound.
// This round: (a) global_load_lds width-16 staging (m97), (b) XOR bank-swizzle
// of the LDS tile (global-side permuted for g2l compatibility).

typedef __bf16 bf16x8 __attribute__((ext_vector_type(8)));
typedef float  f32x4  __attribute__((ext_vector_type(4)));

__device__ __forceinline__ float bfbits2f(unsigned int u) {
  union { unsigned int i; float f; } c; c.i = u << 16; return c.f;
}
__device__ __forceinline__ unsigned short f2bfbits(float f) {
  __hip_bfloat16 h = __float2bfloat16(f);
  return __builtin_bit_cast(unsigned short, h);
}

// async global->LDS, 16B per lane. LDS dest = wave-uniform base + lane*16.
__device__ __forceinline__ void g2l16(const void* g, void* l) {
  __builtin_amdgcn_global_load_lds((__attribute__((address_space(1))) void*)g,
                                   (__attribute__((address_space(3))) void*)l,
                                   16, 0, 0);
}

// fp32 -> bf16 conversion, 4 elems/thread (n % 4 == 0 for all our inputs)
__global__ __launch_bounds__(256)
void cvt_k(const float* __restrict__ in, __hip_bfloat16* __restrict__ out, int n)
{
  int i = (blockIdx.x * 256 + threadIdx.x) * 4;
  if (i >= n) return;
  float4 v = *(const float4*)(in + i);
  uint2 o;
  o.x = (unsigned)f2bfbits(v.x) | ((unsigned)f2bfbits(v.y) << 16);
  o.y = (unsigned)f2bfbits(v.z) | ((unsigned)f2bfbits(v.w) << 16);
  *(uint2*)(out + i) = o;
}

// ---------------------------------------------------------------------------
// GEMM: C[M,N] = A[M,K] @ B[N,K]^T + bias[N]  (optional ReLU). A,B bf16
// (B dense [N,K]), bias fp32, C bf16 (OUTF32=0) or fp32 (OUTF32=1), fp32
// accumulate. 128x128 tile, BK=32, 256 thr, 4 waves x (4x4) MFMA 16x16x32.
// Staging: global_load_lds width=16 (m97). LDS tile is XOR-swizzled:
// logical 16B chunk (row, c) lives at physical chunk c ^ ((row>>1)&3), so
// 8-lane issue groups of the ds_read_b128 fragment reads cover all 32 banks
// (r6 counter: 6.29M conflicts -> expect ~0). g2l16 writes physical slots in
// lane order, so the SOURCE column is permuted per lane (same 64B segments,
// coalescing unchanged). M%128==0, K%32==0 required; N edge via clamped
// loads + guarded stores.
// ---------------------------------------------------------------------------
template<int RELU, int OUTF32>
__global__ __launch_bounds__(256, 2)
void gemm_bt(const __hip_bfloat16* __restrict__ A, int lda,
             const __hip_bfloat16* __restrict__ B,
             const float* __restrict__ bias,
             void* __restrict__ Cp, int ldc,
             int M, int N, int K)
{
  __shared__ __align__(16) __hip_bfloat16 As[128 * 32];
  __shared__ __align__(16) __hip_bfloat16 Bs[128 * 32];

  const int tid  = threadIdx.x;
  const int lane = tid & 63;
  const int wave = tid >> 6;
  const int quad = lane >> 4;
  const int l16  = lane & 15;
  const int m0 = blockIdx.y * 128;
  const int n0 = blockIdx.x * 128;
  const int wr = (wave >> 1) * 64;   // wave's 64x64 sub-tile
  const int wc = (wave & 1) * 64;

  // physical chunk p (16B LDS slot) = row*4 + pc; wave w's lanes fill slots
  // w*64+lane and w*64+256+lane. Source logical col8 = pc ^ ((row>>1)&3).
  const int p0  = wave * 64 + lane;
  const int p1  = p0 + 256;
  const int ar0 = p0 >> 2, ac0 = (((p0 & 3) ^ ((ar0 >> 1) & 3))) * 8;
  const int ar1 = p1 >> 2, ac1 = (((p1 & 3) ^ ((ar1 >> 1) & 3))) * 8;
  const int br0 = min(n0 + ar0, N - 1);   // clamp for N edge (loads valid
  const int br1 = min(n0 + ar1, N - 1);   // data; stores are guarded)
  __hip_bfloat16* lA0 = &As[(wave * 64)       * 8];
  __hip_bfloat16* lA1 = &As[(wave * 64 + 256) * 8];
  __hip_bfloat16* lB0 = &Bs[(wave * 64)       * 8];
  __hip_bfloat16* lB1 = &Bs[(wave * 64 + 256) * 8];

  f32x4 acc[4][4] = {};

  for (int k0 = 0; k0 < K; k0 += 32) {
    g2l16(A + (size_t)(m0 + ar0) * lda + k0 + ac0, lA0);
    g2l16(A + (size_t)(m0 + ar1) * lda + k0 + ac1, lA1);
    g2l16(B + (size_t)br0 * K + k0 + ac0, lB0);
    g2l16(B + (size_t)br1 * K + k0 + ac1, lB1);
    __syncthreads();   // drains vmcnt (global_load_lds) + barrier

    bf16x8 af[4], bfr[4];
#pragma unroll
    for (int i = 0; i < 4; i++) {  // A frag: lane holds A[m=row][k=quad*8..+7]
      const int row = wr + i * 16 + l16;
      af[i] = *(const bf16x8*)&As[row * 32 + ((quad ^ ((row >> 1) & 3)) * 8)];
    }
#pragma unroll
    for (int j = 0; j < 4; j++) {  // B frag: lane holds B[n=row][k=quad*8..+7]
      const int row = wc + j * 16 + l16;
      bfr[j] = *(const bf16x8*)&Bs[row * 32 + ((quad ^ ((row >> 1) & 3)) * 8)];
    }
#pragma unroll
    for (int i = 0; i < 4; i++)
#pragma unroll
      for (int j = 0; j < 4; j++)
        acc[i][j] = __builtin_amdgcn_mfma_f32_16x16x32_bf16(af[i], bfr[j], acc[i][j], 0, 0, 0);
    __syncthreads();   // all frag reads done before next tile's g2l writes
  }

  // epilogue: C/D layout col = lane&15, row = quad*4 + reg
#pragma unroll
  for (int j = 0; j < 4; j++) {
    int col = n0 + wc + j * 16 + l16;
    if (col < N) {
      float bv = bias[col];
#pragma unroll
      for (int i = 0; i < 4; i++) {
        int row = m0 + wr + i * 16 + quad * 4;
#pragma unroll
        for (int r = 0; r < 4; r++) {
          float v = acc[i][j][r] + bv;
          if (RELU) v = fmaxf(v, 0.f);
          if (OUTF32) ((float*)Cp)[(size_t)(row + r) * ldc + col] = v;
          else ((__hip_bfloat16*)Cp)[(size_t)(row + r) * ldc + col] = __float2bfloat16(v);
        }
      }
    }
  }
}

// ---------------------------------------------------------------------------
// Banded attention: one wave per (s, b, h); seq-major rows (row = s*B+b).
// Window = 5 keys (j in [s-4, s]). dh=256 => 4 elems/lane. qkv rows [3H]:
// q@0, k@H, v@2H; head h at h*256. ctx overwrites the q slot.
// ---------------------------------------------------------------------------
__global__ __launch_bounds__(256)
void attn_k(__hip_bfloat16* __restrict__ qkv)
{
  const int gw   = (blockIdx.x << 2) + (threadIdx.x >> 6);
  const int lane = threadIdx.x & 63;
  const int h = gw & (NHEADS - 1);
  const int b = (gw >> 2) & (BATCH - 1);
  const int s = gw >> 4;
  const size_t hoff = (size_t)h * DHEAD + (lane << 2);

  float q0, q1, q2, q3;
  {
    uint2 t = *(const uint2*)(qkv + (size_t)(s * BATCH + b) * QKV_LD + hoff);
    q0 = bfbits2f(t.x & 0xffff); q1 = bfbits2f(t.x >> 16);
    q2 = bfbits2f(t.y & 0xffff); q3 = bfbits2f(t.y >> 16);
  }

  float sc[WIN + 1];
#pragma unroll
  for (int jj = 0; jj <= WIN; jj++) {
    int j = s - WIN + jj;           // wave-uniform
    float v = -1e30f;
    if (j >= 0) {
      uint2 t = *(const uint2*)(qkv + (size_t)(j * BATCH + b) * QKV_LD + H_DIM + hoff);
      float p = q0 * bfbits2f(t.x & 0xffff) + q1 * bfbits2f(t.x >> 16)
              + q2 * bfbits2f(t.y & 0xffff) + q3 * bfbits2f(t.y >> 16);
#pragma unroll
      for (int o = 32; o; o >>= 1) p += __shfl_xor(p, o);
      v = p * 0.0625f;              // 1/sqrt(256)
    }
    sc[jj] = v;
  }

  float mx = sc[0];
#pragma unroll
  for (int jj = 1; jj <= WIN; jj++) mx = fmaxf(mx, sc[jj]);
  float p[WIN + 1], den = 0.f;
#pragma unroll
  for (int jj = 0; jj <= WIN; jj++) { p[jj] = __expf(sc[jj] - mx); den += p[jj]; }

  float a0 = 0.f, a1 = 0.f, a2 = 0.f, a3 = 0.f;
#pragma unroll
  for (int jj = 0; jj <= WIN; jj++) {
    int j = s - WIN + jj;
    if (j >= 0) {
      uint2 t = *(const uint2*)(qkv + (size_t)(j * BATCH + b) * QKV_LD + 2 * H_DIM + hoff);
      a0 += p[jj] * bfbits2f(t.x & 0xffff); a1 += p[jj] * bfbits2f(t.x >> 16);
      a2 += p[jj] * bfbits2f(t.y & 0xffff); a3 += p[jj] * bfbits2f(t.y >> 16);
    }
  }
  float rl = 1.f / den;
  uint2 o;
  o.x = (unsigned)f2bfbits(a0 * rl) | ((unsigned)f2bfbits(a1 * rl) << 16);
  o.y = (unsigned)f2bfbits(a2 * rl) | ((unsigned)f2bfbits(a3 * rl) << 16);
  *(uint2*)(qkv + (size_t)(s * BATCH + b) * QKV_LD + hoff) = o;  // ctx -> q slot
}

// ---------------------------------------------------------------------------
// Fused residual-add + LayerNorm, in place on bf16 x. One block per row.
// ---------------------------------------------------------------------------
__global__ __launch_bounds__(256)
void add_ln_k(__hip_bfloat16* __restrict__ x, const __hip_bfloat16* __restrict__ y, int ys,
              const float* __restrict__ g, const float* __restrict__ be)
{
  const int row = blockIdx.x, tid = threadIdx.x;
  const size_t base = (size_t)row * H_DIM + tid * 4;
  uint2 xv = *(const uint2*)(x + base);
  uint2 yv = *(const uint2*)(y + (size_t)row * ys + tid * 4);
  float t0 = bfbits2f(xv.x & 0xffff) + bfbits2f(yv.x & 0xffff);
  float t1 = bfbits2f(xv.x >> 16)    + bfbits2f(yv.x >> 16);
  float t2 = bfbits2f(xv.y & 0xffff) + bfbits2f(yv.y & 0xffff);
  float t3 = bfbits2f(xv.y >> 16)    + bfbits2f(yv.y >> 16);
  float s  = t0 + t1 + t2 + t3;
  float ss = t0 * t0 + t1 * t1 + t2 * t2 + t3 * t3;
#pragma unroll
  for (int o = 32; o; o >>= 1) { s += __shfl_down(s, o); ss += __shfl_down(ss, o); }
  __shared__ float rs[4], rss[4];
  if ((tid & 63) == 0) { rs[tid >> 6] = s; rss[tid >> 6] = ss; }
  __syncthreads();
  float S  = rs[0] + rs[1] + rs[2] + rs[3];
  float SS = rss[0] + rss[1] + rss[2] + rss[3];
  const float inv = 1.f / (float)H_DIM;
  float mean = S * inv;
  float var  = SS * inv - mean * mean;       // biased var (jnp.var default)
  float rstd = rsqrtf(var + 1e-5f);
  float4 gv = *(const float4*)(g + tid * 4);
  float4 bv = *(const float4*)(be + tid * 4);
  float o0 = (t0 - mean) * rstd * gv.x + bv.x;
  float o1 = (t1 - mean) * rstd * gv.y + bv.y;
  float o2 = (t2 - mean) * rstd * gv.z + bv.z;
  float o3 = (t3 - mean) * rstd * gv.w + bv.w;
  uint2 ob;
  ob.x = (unsigned)f2bfbits(o0) | ((unsigned)f2bfbits(o1) << 16);
  ob.y = (unsigned)f2bfbits(o2) | ((unsigned)f2bfbits(o3) << 16);
  *(uint2*)(x + base) = ob;
}

// ---------------------------------------------------------------------------
extern "C" void kernel_launch(void* const* d_in, const int* in_sizes, int n_in,
                              void* d_out, int out_size, void* d_ws, size_t ws_size,
                              hipStream_t stream) {
  const float* src   = (const float*)d_in[0];
  const float* Wenc  = (const float*)d_in[1];
  const float* benc  = (const float*)d_in[2];
  const float* Wqkv  = (const float*)d_in[3];
  const float* bqkv  = (const float*)d_in[4];
  const float* Wo    = (const float*)d_in[5];
  const float* bo    = (const float*)d_in[6];
  const float* W1    = (const float*)d_in[7];
  const float* b1    = (const float*)d_in[8];
  const float* W2    = (const float*)d_in[9];
  const float* b2    = (const float*)d_in[10];
  const float* ln1s  = (const float*)d_in[11];
  const float* ln1b  = (const float*)d_in[12];
  const float* ln2s  = (const float*)d_in[13];
  const float* ln2b  = (const float*)d_in[14];
  const float* Wout  = (const float*)d_in[15];
  const float* bout  = (const float*)d_in[16];

  // ---- workspace (104 MiB total — footprint validated rounds 3/6) ----
  char* ws = (char*)d_ws;
  __hip_bfloat16* WB   = (__hip_bfloat16*)ws;      // bf16 arena (~37.3 MiB)
  __hip_bfloat16* srcb = WB;                       //   524288
  __hip_bfloat16* wenc = WB + 524288;              //    65536
  __hip_bfloat16* wqkv = WB + 589824;              //  9437184
  __hip_bfloat16* wo   = WB + 10027008;            //  3145728
  __hip_bfloat16* w1   = WB + 13172736;            //  3145728
  __hip_bfloat16* w2   = WB + 16318464;            //  3145728
  __hip_bfloat16* wout = WB + 19464192;            //    65536
  __hip_bfloat16* xb  = (__hip_bfloat16*)(ws + (size_t)40 * 1048576);  // 16 MiB
  __hip_bfloat16* qkv = (__hip_bfloat16*)(ws + (size_t)56 * 1048576);  // 48 MiB
  __hip_bfloat16* ctxp = qkv;             // q slot — attn output
  __hip_bfloat16* ybuf = qkv + H_DIM;     // k slot — attn_out / ff temp
  __hip_bfloat16* hbuf = qkv + 2 * H_DIM; // v slot — relu hidden temp

  const dim3 blk(256);
  #define CVT(inp, outp, n) cvt_k<<<dim3(((n) / 4 + 255) / 256), blk, 0, stream>>>(inp, outp, n)

  // ---- ingest: fp32 weights/src -> bf16 arenas (biases/LN stay fp32) ----
  CVT(src,  srcb, 524288);
  CVT(Wenc, wenc, 65536);
  CVT(Wqkv, wqkv, 9437184);
  CVT(Wo,   wo,   3145728);
  CVT(W1,   w1,   3145728);
  CVT(W2,   w2,   3145728);
  CVT(Wout, wout, 65536);

  // ---- encoder: x = src @ Wenc^T + benc   [8192,1024] ----
  gemm_bt<0, 0><<<dim3(H_DIM / 128, ROWS / 128), blk, 0, stream>>>(
      srcb, IN_DIM, wenc, benc, xb, H_DIM, ROWS, H_DIM, IN_DIM);

  for (int l = 0; l < NLAYER; l++) {
    // qkv = x @ Wqkv^T + bqkv   [8192,3072]
    gemm_bt<0, 0><<<dim3(QKV_LD / 128, ROWS / 128), blk, 0, stream>>>(
        xb, H_DIM, wqkv + (size_t)l * QKV_LD * H_DIM, bqkv + l * QKV_LD,
        qkv, QKV_LD, ROWS, QKV_LD, H_DIM);
    // banded attention; ctx -> q slot
    attn_k<<<dim3(ROWS * NHEADS / 4), blk, 0, stream>>>(qkv);
    // attn_out = ctx @ Wo^T + bo -> ybuf (k slot)
    gemm_bt<0, 0><<<dim3(H_DIM / 128, ROWS / 128), blk, 0, stream>>>(
        ctxp, QKV_LD, wo + (size_t)l * H_DIM * H_DIM, bo + l * H_DIM,
        ybuf, QKV_LD, ROWS, H_DIM, H_DIM);
    // x = LN(x + attn_out)
    add_ln_k<<<dim3(ROWS), blk, 0, stream>>>(xb, ybuf, QKV_LD, ln1s + l * H_DIM, ln1b + l * H_DIM);
    // h = relu(x @ W1^T + b1) -> hbuf (v slot)
    gemm_bt<1, 0><<<dim3(DFF_DIM / 128, ROWS / 128), blk, 0, stream>>>(
        xb, H_DIM, w1 + (size_t)l * DFF_DIM * H_DIM, b1 + l * DFF_DIM,
        hbuf, QKV_LD, ROWS, DFF_DIM, H_DIM);
    // ff = h @ W2^T + b2 -> ybuf (k slot)
    gemm_bt<0, 0><<<dim3(H_DIM / 128, ROWS / 128), blk, 0, stream>>>(
        hbuf, QKV_LD, w2 + (size_t)l * H_DIM * DFF_DIM, b2 + l * H_DIM,
        ybuf, QKV_LD, ROWS, H_DIM, DFF_DIM);
    // x = LN(x + ff)
    add_ln_k<<<dim3(ROWS), blk, 0, stream>>>(xb, ybuf, QKV_LD, ln2s + l * H_DIM, ln2b + l * H_DIM);
  }

  // ---- decoder: out = x @ Wout^T + bout   [8192,64] FP32 OUTPUT ----
  gemm_bt<0, 1><<<dim3(1, ROWS / 128), blk, 0, stream>>>(
      xb, H_DIM, wout, bout, d_out, OUT_DIM, ROWS, OUT_DIM, H_DIM);
}